// Round 1
// baseline (1180.123 us; speedup 1.0000x reference)
//
#include <hip/hip_runtime.h>

#define CDIV(a,b) (((a)+(b)-1)/(b))

// ---------------- CSR build ----------------

__global__ __launch_bounds__(256) void count_deg_k(const int* __restrict__ dst, int E,
                                                   int* __restrict__ degc) {
    int stride = gridDim.x * blockDim.x;
    for (int i = blockIdx.x * blockDim.x + threadIdx.x; i < E; i += stride)
        atomicAdd(&degc[dst[i]], 1);
}

// dinv = rsqrt(indeg+1); start[v] = atomic segment allocation (order irrelevant)
__global__ __launch_bounds__(256) void alloc_k(const int* __restrict__ degc,
                                               float* __restrict__ dinv,
                                               int* __restrict__ start,
                                               int* __restrict__ cursor,
                                               int* __restrict__ total, int N) {
    int stride = gridDim.x * blockDim.x;
    for (int i = blockIdx.x * blockDim.x + threadIdx.x; i < N; i += stride) {
        int c = degc[i];
        dinv[i] = rsqrtf((float)(c + 1));
        int s = atomicAdd(total, c);
        start[i]  = s;
        cursor[i] = s;
    }
}

__global__ __launch_bounds__(256) void fill_k(const int* __restrict__ src,
                                              const int* __restrict__ dst, int E,
                                              int* __restrict__ cursor,
                                              int* __restrict__ csr) {
    int stride = gridDim.x * blockDim.x;
    for (int i = blockIdx.x * blockDim.x + threadIdx.x; i < E; i += stride) {
        int p = atomicAdd(&cursor[dst[i]], 1);
        csr[p] = src[i];
    }
}

// ---------------- fp32 GEMM: C[N][128] = X[N][K] @ W[K][128] ----------------
// Block tile 64 rows x 128 cols, 256 threads, each thread 4 rows x 8 cols.

template <int K>
__global__ __launch_bounds__(256) void gemm_rm(const float* __restrict__ X,
                                               const float* __restrict__ W,
                                               float* __restrict__ C, int N) {
    constexpr int KC = 32;
    __shared__ float xT[KC][68];   // [k][row], stride 68 floats (16B aligned rows)
    __shared__ float wS[KC][128];  // [k][col]

    const int t   = threadIdx.x;
    const int cg  = t & 15;   // col group: cols 8*cg .. 8*cg+7
    const int rg  = t >> 4;   // row group: rows 4*rg .. 4*rg+3
    const int row0 = blockIdx.x * 64;

    float acc[4][8];
#pragma unroll
    for (int r = 0; r < 4; ++r)
#pragma unroll
        for (int c = 0; c < 8; ++c) acc[r][c] = 0.f;

    for (int kc = 0; kc < K; kc += KC) {
        __syncthreads();
        // stage W chunk (KC x 128) linearly
        for (int i = t; i < KC * 128 / 4; i += 256) {
            reinterpret_cast<float4*>(wS)[i] =
                reinterpret_cast<const float4*>(W + (size_t)kc * 128)[i];
        }
        // stage X chunk transposed: xT[k][row]
        for (int i = t; i < 64 * KC / 4; i += 256) {
            int r  = i / (KC / 4);
            int kv = (i % (KC / 4)) * 4;
            float4 v = make_float4(0.f, 0.f, 0.f, 0.f);
            int row = row0 + r;
            if (row < N)
                v = *reinterpret_cast<const float4*>(X + (size_t)row * K + kc + kv);
            xT[kv + 0][r] = v.x;
            xT[kv + 1][r] = v.y;
            xT[kv + 2][r] = v.z;
            xT[kv + 3][r] = v.w;
        }
        __syncthreads();

#pragma unroll
        for (int kk = 0; kk < KC; ++kk) {
            float4 xv = *reinterpret_cast<const float4*>(&xT[kk][rg * 4]);
            float4 wa = *reinterpret_cast<const float4*>(&wS[kk][cg * 8]);
            float4 wb = *reinterpret_cast<const float4*>(&wS[kk][cg * 8 + 4]);
            float xr[4] = {xv.x, xv.y, xv.z, xv.w};
            float wc[8] = {wa.x, wa.y, wa.z, wa.w, wb.x, wb.y, wb.z, wb.w};
#pragma unroll
            for (int r = 0; r < 4; ++r)
#pragma unroll
                for (int c = 0; c < 8; ++c)
                    acc[r][c] = fmaf(xr[r], wc[c], acc[r][c]);
        }
    }

    const int rb = row0 + rg * 4;
#pragma unroll
    for (int r = 0; r < 4; ++r) {
        int row = rb + r;
        if (row < N) {
            float4 o0 = make_float4(acc[r][0], acc[r][1], acc[r][2], acc[r][3]);
            float4 o1 = make_float4(acc[r][4], acc[r][5], acc[r][6], acc[r][7]);
            *reinterpret_cast<float4*>(C + (size_t)row * 128 + cg * 8)     = o0;
            *reinterpret_cast<float4*>(C + (size_t)row * 128 + cg * 8 + 4) = o1;
        }
    }
}

// ---------------- aggregation: one wave per node ----------------
// out[v] = dinv[v] * (dinv[v]*h[v] + sum_e dinv[src_e]*h[src_e]) + bias, optional relu

__global__ __launch_bounds__(256) void agg_k(const float* __restrict__ Hin,
                                             float* __restrict__ Hout,
                                             const int* __restrict__ csr,
                                             const int* __restrict__ start,
                                             const int* __restrict__ degc,
                                             const float* __restrict__ dinv,
                                             const float* __restrict__ bias,
                                             int N, int relu) {
    int wid  = threadIdx.x >> 6;
    int lane = threadIdx.x & 63;
    int v = blockIdx.x * 4 + wid;
    if (v >= N) return;

    float dv = dinv[v];
    int s = start[v];
    int c = degc[v];

    const float2* base = reinterpret_cast<const float2*>(Hin);
    float2 h = base[(size_t)v * 64 + lane];
    float2 acc = make_float2(dv * h.x, dv * h.y);

    for (int e = s; e < s + c; ++e) {
        int u   = csr[e];
        float w = dinv[u];
        float2 hv = base[(size_t)u * 64 + lane];
        acc.x = fmaf(w, hv.x, acc.x);
        acc.y = fmaf(w, hv.y, acc.y);
    }

    float2 b = reinterpret_cast<const float2*>(bias)[lane];
    float2 o;
    o.x = fmaf(dv, acc.x, b.x);
    o.y = fmaf(dv, acc.y, b.y);
    if (relu) {
        o.x = fmaxf(o.x, 0.f);
        o.y = fmaxf(o.y, 0.f);
    }
    reinterpret_cast<float2*>(Hout)[(size_t)v * 64 + lane] = o;
}

// ---------------- column stats + normalize ----------------

__global__ __launch_bounds__(128) void colstats_k(const float* __restrict__ H,
                                                  float* __restrict__ stats, int N) {
    // stats[0..127] = sums, stats[128..255] = sumsq
    int col = threadIdx.x;
    int r0 = blockIdx.x * 128;
    int r1 = r0 + 128 < N ? r0 + 128 : N;
    float s = 0.f, q = 0.f;
    for (int r = r0; r < r1; ++r) {
        float v = H[(size_t)r * 128 + col];
        s += v;
        q = fmaf(v, v, q);
    }
    atomicAdd(&stats[col], s);
    atomicAdd(&stats[128 + col], q);
}

__global__ __launch_bounds__(256) void colnorm_k(float* __restrict__ H,
                                                 const float* __restrict__ stats, int N) {
    size_t total = (size_t)N * 32;  // float4 count
    float invN = 1.f / (float)N;
    float invNm1 = 1.f / (float)(N - 1);
    size_t stride = (size_t)gridDim.x * blockDim.x;
    for (size_t i = (size_t)blockIdx.x * blockDim.x + threadIdx.x; i < total; i += stride) {
        int cv = (int)(i & 31);
        float4 s = reinterpret_cast<const float4*>(stats)[cv];
        float4 q = reinterpret_cast<const float4*>(stats + 128)[cv];
        float4 v = reinterpret_cast<float4*>(H)[i];
        float mu, rstd;
        mu = s.x * invN; rstd = rsqrtf((q.x - s.x * mu) * invNm1); v.x = (v.x - mu) * rstd;
        mu = s.y * invN; rstd = rsqrtf((q.y - s.y * mu) * invNm1); v.y = (v.y - mu) * rstd;
        mu = s.z * invN; rstd = rsqrtf((q.z - s.z * mu) * invNm1); v.z = (v.z - mu) * rstd;
        mu = s.w * invN; rstd = rsqrtf((q.w - s.w * mu) * invNm1); v.w = (v.w - mu) * rstd;
        reinterpret_cast<float4*>(H)[i] = v;
    }
}

// ---------------- driver ----------------

extern "C" void kernel_launch(void* const* d_in, const int* in_sizes, int n_in,
                              void* d_out, int out_size, void* d_ws, size_t ws_size,
                              hipStream_t stream) {
    const float* x1  = (const float*)d_in[0];
    const int*   ei1 = (const int*)d_in[1];
    const float* x2  = (const float*)d_in[2];
    const int*   ei2 = (const int*)d_in[3];
    const float* W0  = (const float*)d_in[4];
    const float* b0  = (const float*)d_in[5];
    const float* W1  = (const float*)d_in[6];
    const float* b1  = (const float*)d_in[7];

    const int N  = in_sizes[0] / 256;
    const int E1 = in_sizes[1] / 2;
    const int E2 = in_sizes[3] / 2;
    const int Emax = E1 > E2 ? E1 : E2;

    // workspace carve-out (256B aligned)
    char* base = (char*)d_ws;
    size_t off = 0;
    auto carve = [&](size_t bytes) -> char* {
        char* p = base + off;
        off = (off + bytes + 255) & ~(size_t)255;
        return p;
    };
    float* hbuf   = (float*)carve((size_t)N * 128 * 4);
    float* dinv   = (float*)carve((size_t)N * 4);
    int*   degc   = (int*)carve((size_t)N * 4);
    int*   startA = (int*)carve((size_t)N * 4);
    int*   cursor = (int*)carve((size_t)N * 4);
    int*   csr    = (int*)carve((size_t)Emax * 4);
    float* stats  = (float*)carve(256 * 4);
    int*   total  = (int*)carve(256);

    for (int g = 0; g < 2; ++g) {
        const float* x  = g ? x2 : x1;
        const int*   ei = g ? ei2 : ei1;
        const int    E  = g ? E2 : E1;
        float* outg = (float*)d_out + (size_t)g * N * 128;

        hipMemsetAsync(degc, 0, (size_t)N * 4, stream);
        hipMemsetAsync(total, 0, 4, stream);
        hipMemsetAsync(stats, 0, 256 * 4, stream);

        int eb = CDIV(E, 256) < 4096 ? CDIV(E, 256) : 4096;
        count_deg_k<<<eb, 256, 0, stream>>>(ei + E, E, degc);
        alloc_k<<<CDIV(N, 256), 256, 0, stream>>>(degc, dinv, startA, cursor, total, N);
        fill_k<<<eb, 256, 0, stream>>>(ei, ei + E, E, cursor, csr);

        // conv1: h = relu(agg(x@W0) + b0)   (relu(h) staged in outg region)
        gemm_rm<256><<<CDIV(N, 64), 256, 0, stream>>>(x, W0, hbuf, N);
        agg_k<<<CDIV(N, 4), 256, 0, stream>>>(hbuf, outg, csr, startA, degc, dinv, b0, N, 1);

        // conv2: out = agg(h@W1) + b1
        gemm_rm<128><<<CDIV(N, 64), 256, 0, stream>>>(outg, W1, hbuf, N);
        agg_k<<<CDIV(N, 4), 256, 0, stream>>>(hbuf, outg, csr, startA, degc, dinv, b1, N, 0);

        // colnorm in place
        colstats_k<<<CDIV(N, 128), 128, 0, stream>>>(outg, stats, N);
        colnorm_k<<<2048, 256, 0, stream>>>(outg, stats, N);
    }
}

// Round 2
// 935.717 us; speedup vs baseline: 1.2612x; 1.2612x over previous
//
#include <hip/hip_runtime.h>

#define CDIV(a,b) (((a)+(b)-1)/(b))

typedef __bf16 bf16x8 __attribute__((ext_vector_type(8)));
typedef float  f32x4  __attribute__((ext_vector_type(4)));

__device__ __forceinline__ ushort f2bf(float f) {
    uint u = __float_as_uint(f);
    uint r = u + 0x7fffu + ((u >> 16) & 1u);   // RNE
    return (ushort)(r >> 16);
}
__device__ __forceinline__ float bf_lo(uint p) { return __uint_as_float(p << 16); }
__device__ __forceinline__ float bf_hi(uint p) { return __uint_as_float(p & 0xffff0000u); }

// ---------------- CSR build ----------------

__global__ __launch_bounds__(256) void count_deg_k(const int* __restrict__ dst, int E,
                                                   int* __restrict__ degc) {
    int stride = gridDim.x * blockDim.x;
    for (int i = blockIdx.x * blockDim.x + threadIdx.x; i < E; i += stride)
        atomicAdd(&degc[dst[i]], 1);
}

__global__ __launch_bounds__(256) void alloc_k(const int* __restrict__ degc,
                                               float* __restrict__ dinv,
                                               int* __restrict__ start,
                                               int* __restrict__ cursor,
                                               int* __restrict__ total, int N) {
    int stride = gridDim.x * blockDim.x;
    for (int i = blockIdx.x * blockDim.x + threadIdx.x; i < N; i += stride) {
        int c = degc[i];
        dinv[i] = rsqrtf((float)(c + 1));
        int s = atomicAdd(total, c);
        start[i]  = s;
        cursor[i] = s;
    }
}

__global__ __launch_bounds__(256) void fill_k(const int* __restrict__ src,
                                              const int* __restrict__ dst, int E,
                                              int* __restrict__ cursor,
                                              int* __restrict__ csr) {
    int stride = gridDim.x * blockDim.x;
    for (int i = blockIdx.x * blockDim.x + threadIdx.x; i < E; i += stride) {
        int p = atomicAdd(&cursor[dst[i]], 1);
        csr[p] = src[i];
    }
}

// ---------------- W pre-pack: fragment-major bf16 ----------------
// Wp[kb][nf][lane] = 8 bf16 (16B): W[kb*32 + (lane>>4)*8 + j][nf*16 + (lane&15)]

__global__ __launch_bounds__(256) void pack_w_k(const float* __restrict__ W,
                                                ushort* __restrict__ Wp, int K) {
    int idx = blockIdx.x * 256 + threadIdx.x;
    int total = (K / 32) * 8 * 64;
    if (idx >= total) return;
    int l  = idx & 63;
    int nf = (idx >> 6) & 7;
    int kb = idx >> 9;
    int col = nf * 16 + (l & 15);
    int k0  = kb * 32 + (l >> 4) * 8;
    ushort o[8];
#pragma unroll
    for (int j = 0; j < 8; ++j) o[j] = f2bf(W[(size_t)(k0 + j) * 128 + col]);
    *reinterpret_cast<float4*>(Wp + (size_t)idx * 8) = *reinterpret_cast<float4*>(o);
}

// ---------------- MFMA GEMM: C[N][128] = X[N][K] @ W[K][128] ----------------
// 256 thr = 4 waves; block tile 64 rows; wave w owns rows [w*16, w*16+16), all 128 cols.
// TIn: float (convert on stage) or ushort (bf16 passthrough). TOut: ushort bf16 or float.

template <int K, typename TIn, typename TOut>
__global__ __launch_bounds__(256) void gemm_mfma(const TIn* __restrict__ X,
                                                 const float4* __restrict__ Wp,
                                                 TOut* __restrict__ C, int N) {
    constexpr int KB = K / 32;
    __shared__ ushort As[64 * 40];     // row stride 40 shorts (80B): 2-way conflicts only
    __shared__ ushort Bs[8 * 64 * 8];  // 8KB: one kb-slice of Wp

    const int t    = threadIdx.x;
    const int lane = t & 63;
    const int w    = t >> 6;
    const int row0 = blockIdx.x * 64;

    f32x4 acc[8] = {};

    const int sr = t >> 2;  // staging row 0..63
    const int sc = t & 3;   // k-chunk 0..3 (8 elems each)

    for (int kb = 0; kb < KB; ++kb) {
        __syncthreads();
        // stage A (64 x 32) as bf16
        {
            int grow = row0 + sr;
            ushort av[8];
            if (grow < N) {
                if constexpr (sizeof(TIn) == 4) {
                    const float* px = (const float*)X + (size_t)grow * K + kb * 32 + sc * 8;
                    float4 v0 = *reinterpret_cast<const float4*>(px);
                    float4 v1 = *reinterpret_cast<const float4*>(px + 4);
                    av[0] = f2bf(v0.x); av[1] = f2bf(v0.y); av[2] = f2bf(v0.z); av[3] = f2bf(v0.w);
                    av[4] = f2bf(v1.x); av[5] = f2bf(v1.y); av[6] = f2bf(v1.z); av[7] = f2bf(v1.w);
                } else {
                    const ushort* px = (const ushort*)X + (size_t)grow * K + kb * 32 + sc * 8;
                    *reinterpret_cast<float4*>(av) = *reinterpret_cast<const float4*>(px);
                }
            } else {
#pragma unroll
                for (int j = 0; j < 8; ++j) av[j] = 0;
            }
            *reinterpret_cast<float4*>(&As[sr * 40 + sc * 8]) = *reinterpret_cast<float4*>(av);
        }
        // stage B slice (8 frags x 64 lanes x 16B = 8KB)
        {
            const float4* src = Wp + (size_t)kb * 512;
            reinterpret_cast<float4*>(Bs)[t]       = src[t];
            reinterpret_cast<float4*>(Bs)[t + 256] = src[t + 256];
        }
        __syncthreads();

        bf16x8 a = *reinterpret_cast<const bf16x8*>(
            &As[(w * 16 + (lane & 15)) * 40 + (lane >> 4) * 8]);
#pragma unroll
        for (int nf = 0; nf < 8; ++nf) {
            bf16x8 b = *reinterpret_cast<const bf16x8*>(&Bs[(nf * 64 + lane) * 8]);
            acc[nf] = __builtin_amdgcn_mfma_f32_16x16x32_bf16(a, b, acc[nf], 0, 0, 0);
        }
    }

    // write C: col = lane&15, row = (lane>>4)*4 + reg
    const int crow0 = row0 + w * 16 + ((lane >> 4) << 2);
    const int col   = lane & 15;
#pragma unroll
    for (int i = 0; i < 4; ++i) {
        int row = crow0 + i;
        if (row < N) {
#pragma unroll
            for (int nf = 0; nf < 8; ++nf) {
                float v = acc[nf][i];
                if constexpr (sizeof(TOut) == 2)
                    C[(size_t)row * 128 + nf * 16 + col] = (TOut)f2bf(v);
                else
                    C[(size_t)row * 128 + nf * 16 + col] = (TOut)v;
            }
        }
    }
}

// ---------------- aggregation (bf16 gather): one wave per node ----------------

template <typename TOut>
__global__ __launch_bounds__(256) void agg_k(const ushort* __restrict__ Hin,
                                             TOut* __restrict__ Hout,
                                             const int* __restrict__ csr,
                                             const int* __restrict__ start,
                                             const int* __restrict__ degc,
                                             const float* __restrict__ dinv,
                                             const float* __restrict__ bias,
                                             int N, int relu) {
    int wid  = threadIdx.x >> 6;
    int lane = threadIdx.x & 63;
    int v = blockIdx.x * 4 + wid;
    if (v >= N) return;

    float dv = dinv[v];
    int s = start[v];
    int c = degc[v];

    const uint* base = reinterpret_cast<const uint*>(Hin);  // 2 bf16 per lane
    uint hp = base[(size_t)v * 64 + lane];
    float ax = dv * bf_lo(hp);
    float ay = dv * bf_hi(hp);

    for (int e = s; e < s + c; ++e) {
        int u   = csr[e];
        float wt = dinv[u];
        uint p = base[(size_t)u * 64 + lane];
        ax = fmaf(wt, bf_lo(p), ax);
        ay = fmaf(wt, bf_hi(p), ay);
    }

    float2 b = reinterpret_cast<const float2*>(bias)[lane];
    float ox = fmaf(dv, ax, b.x);
    float oy = fmaf(dv, ay, b.y);
    if (relu) {
        ox = fmaxf(ox, 0.f);
        oy = fmaxf(oy, 0.f);
    }
    if constexpr (sizeof(TOut) == 2) {
        uint packed = (uint)f2bf(ox) | ((uint)f2bf(oy) << 16);
        reinterpret_cast<uint*>(Hout)[(size_t)v * 64 + lane] = packed;
    } else {
        reinterpret_cast<float2*>(Hout)[(size_t)v * 64 + lane] = make_float2(ox, oy);
    }
}

// ---------------- column stats + normalize ----------------

__global__ __launch_bounds__(128) void colstats_k(const float* __restrict__ H,
                                                  float* __restrict__ stats, int N) {
    int col = threadIdx.x;
    int r0 = blockIdx.x * 128;
    int r1 = r0 + 128 < N ? r0 + 128 : N;
    float s = 0.f, q = 0.f;
    for (int r = r0; r < r1; ++r) {
        float v = H[(size_t)r * 128 + col];
        s += v;
        q = fmaf(v, v, q);
    }
    atomicAdd(&stats[col], s);
    atomicAdd(&stats[128 + col], q);
}

__global__ __launch_bounds__(256) void colnorm_k(float* __restrict__ H,
                                                 const float* __restrict__ stats, int N) {
    size_t total = (size_t)N * 32;
    float invN = 1.f / (float)N;
    float invNm1 = 1.f / (float)(N - 1);
    size_t stride = (size_t)gridDim.x * blockDim.x;
    for (size_t i = (size_t)blockIdx.x * blockDim.x + threadIdx.x; i < total; i += stride) {
        int cv = (int)(i & 31);
        float4 s = reinterpret_cast<const float4*>(stats)[cv];
        float4 q = reinterpret_cast<const float4*>(stats + 128)[cv];
        float4 v = reinterpret_cast<float4*>(H)[i];
        float mu, rstd;
        mu = s.x * invN; rstd = rsqrtf((q.x - s.x * mu) * invNm1); v.x = (v.x - mu) * rstd;
        mu = s.y * invN; rstd = rsqrtf((q.y - s.y * mu) * invNm1); v.y = (v.y - mu) * rstd;
        mu = s.z * invN; rstd = rsqrtf((q.z - s.z * mu) * invNm1); v.z = (v.z - mu) * rstd;
        mu = s.w * invN; rstd = rsqrtf((q.w - s.w * mu) * invNm1); v.w = (v.w - mu) * rstd;
        reinterpret_cast<float4*>(H)[i] = v;
    }
}

// ---------------- driver ----------------

extern "C" void kernel_launch(void* const* d_in, const int* in_sizes, int n_in,
                              void* d_out, int out_size, void* d_ws, size_t ws_size,
                              hipStream_t stream) {
    const float* x1  = (const float*)d_in[0];
    const int*   ei1 = (const int*)d_in[1];
    const float* x2  = (const float*)d_in[2];
    const int*   ei2 = (const int*)d_in[3];
    const float* W0  = (const float*)d_in[4];
    const float* b0  = (const float*)d_in[5];
    const float* W1  = (const float*)d_in[6];
    const float* b1  = (const float*)d_in[7];

    const int N  = in_sizes[0] / 256;
    const int E1 = in_sizes[1] / 2;
    const int E2 = in_sizes[3] / 2;
    const int Emax = E1 > E2 ? E1 : E2;

    char* base = (char*)d_ws;
    size_t off = 0;
    auto carve = [&](size_t bytes) -> char* {
        char* p = base + off;
        off = (off + bytes + 255) & ~(size_t)255;
        return p;
    };
    ushort* hA    = (ushort*)carve((size_t)N * 128 * 2);   // bf16 h buffers
    ushort* hB    = (ushort*)carve((size_t)N * 128 * 2);
    float*  dinv  = (float*)carve((size_t)N * 4);
    int*    degc  = (int*)carve((size_t)N * 4);
    int*    startA= (int*)carve((size_t)N * 4);
    int*    cursor= (int*)carve((size_t)N * 4);
    int*    csr   = (int*)carve((size_t)Emax * 4);
    ushort* Wp0   = (ushort*)carve((256 / 32) * 8 * 64 * 8 * 2);
    ushort* Wp1   = (ushort*)carve((128 / 32) * 8 * 64 * 8 * 2);
    float*  stats = (float*)carve(256 * 4);
    int*    total = (int*)carve(256);

    // pack weights once (shared by both graphs)
    pack_w_k<<<CDIV((256 / 32) * 8 * 64, 256), 256, 0, stream>>>(W0, Wp0, 256);
    pack_w_k<<<CDIV((128 / 32) * 8 * 64, 256), 256, 0, stream>>>(W1, Wp1, 128);

    for (int g = 0; g < 2; ++g) {
        const float* x  = g ? x2 : x1;
        const int*   ei = g ? ei2 : ei1;
        const int    E  = g ? E2 : E1;
        float* outg = (float*)d_out + (size_t)g * N * 128;

        hipMemsetAsync(degc, 0, (size_t)N * 4, stream);
        hipMemsetAsync(total, 0, 4, stream);
        hipMemsetAsync(stats, 0, 256 * 4, stream);

        int eb = CDIV(E, 256) < 4096 ? CDIV(E, 256) : 4096;
        count_deg_k<<<eb, 256, 0, stream>>>(ei + E, E, degc);
        alloc_k<<<CDIV(N, 256), 256, 0, stream>>>(degc, dinv, startA, cursor, total, N);
        fill_k<<<eb, 256, 0, stream>>>(ei, ei + E, E, cursor, csr);

        // conv1: hA = x @ W0 (bf16) ; hB = relu(agg(hA) + b0) (bf16)
        gemm_mfma<256, float, ushort><<<CDIV(N, 64), 256, 0, stream>>>(
            x, (const float4*)Wp0, hA, N);
        agg_k<ushort><<<CDIV(N, 4), 256, 0, stream>>>(hA, hB, csr, startA, degc, dinv, b0, N, 1);

        // conv2: hA = hB @ W1 (bf16) ; out = agg(hA) + b1 (f32)
        gemm_mfma<128, ushort, ushort><<<CDIV(N, 64), 256, 0, stream>>>(
            hB, (const float4*)Wp1, hA, N);
        agg_k<float><<<CDIV(N, 4), 256, 0, stream>>>(hA, outg, csr, startA, degc, dinv, b1, N, 0);

        // colnorm in place
        colstats_k<<<CDIV(N, 128), 128, 0, stream>>>(outg, stats, N);
        colnorm_k<<<2048, 256, 0, stream>>>(outg, stats, N);
    }
}

// Round 3
// 708.759 us; speedup vs baseline: 1.6651x; 1.3202x over previous
//
#include <hip/hip_runtime.h>

#define CDIV(a,b) (((a)+(b)-1)/(b))

typedef __bf16 bf16x8 __attribute__((ext_vector_type(8)));
typedef float  f32x4  __attribute__((ext_vector_type(4)));

__device__ __forceinline__ ushort f2bf(float f) {
    uint u = __float_as_uint(f);
    uint r = u + 0x7fffu + ((u >> 16) & 1u);   // RNE
    return (ushort)(r >> 16);
}
__device__ __forceinline__ float bf_lo(uint p) { return __uint_as_float(p << 16); }
__device__ __forceinline__ float bf_hi(uint p) { return __uint_as_float(p & 0xffff0000u); }

// ---------------- CSR build ----------------

__global__ __launch_bounds__(256) void count_deg_k(const int* __restrict__ dst, int E,
                                                   int* __restrict__ degc) {
    int stride = gridDim.x * blockDim.x;
    for (int i = blockIdx.x * blockDim.x + threadIdx.x; i < E; i += stride)
        atomicAdd(&degc[dst[i]], 1);
}

__global__ __launch_bounds__(256) void alloc_k(const int* __restrict__ degc,
                                               float* __restrict__ dinv,
                                               int* __restrict__ start,
                                               int* __restrict__ cursor,
                                               int* __restrict__ total, int N) {
    int stride = gridDim.x * blockDim.x;
    for (int i = blockIdx.x * blockDim.x + threadIdx.x; i < N; i += stride) {
        int c = degc[i];
        dinv[i] = rsqrtf((float)(c + 1));
        int s = atomicAdd(total, c);
        start[i]  = s;
        cursor[i] = s;
    }
}

__global__ __launch_bounds__(256) void fill_k(const int* __restrict__ src,
                                              const int* __restrict__ dst, int E,
                                              int* __restrict__ cursor,
                                              int* __restrict__ csr) {
    int stride = gridDim.x * blockDim.x;
    for (int i = blockIdx.x * blockDim.x + threadIdx.x; i < E; i += stride) {
        int p = atomicAdd(&cursor[dst[i]], 1);
        csr[p] = src[i];
    }
}

// ---------------- W pre-pack: fragment-major bf16 ----------------

__global__ __launch_bounds__(256) void pack_w_k(const float* __restrict__ W,
                                                ushort* __restrict__ Wp, int K) {
    int idx = blockIdx.x * 256 + threadIdx.x;
    int total = (K / 32) * 8 * 64;
    if (idx >= total) return;
    int l  = idx & 63;
    int nf = (idx >> 6) & 7;
    int kb = idx >> 9;
    int col = nf * 16 + (l & 15);
    int k0  = kb * 32 + (l >> 4) * 8;
    ushort o[8];
#pragma unroll
    for (int j = 0; j < 8; ++j) o[j] = f2bf(W[(size_t)(k0 + j) * 128 + col]);
    *reinterpret_cast<float4*>(Wp + (size_t)idx * 8) = *reinterpret_cast<float4*>(o);
}

// ---------------- MFMA GEMM: C[N][128] = X[N][K] @ W[K][128] ----------------

template <int K, typename TIn, typename TOut>
__global__ __launch_bounds__(256) void gemm_mfma(const TIn* __restrict__ X,
                                                 const float4* __restrict__ Wp,
                                                 TOut* __restrict__ C, int N) {
    constexpr int KB = K / 32;
    __shared__ ushort As[64 * 40];
    __shared__ ushort Bs[8 * 64 * 8];

    const int t    = threadIdx.x;
    const int lane = t & 63;
    const int w    = t >> 6;
    const int row0 = blockIdx.x * 64;

    f32x4 acc[8] = {};

    const int sr = t >> 2;
    const int sc = t & 3;

    for (int kb = 0; kb < KB; ++kb) {
        __syncthreads();
        {
            int grow = row0 + sr;
            ushort av[8];
            if (grow < N) {
                if constexpr (sizeof(TIn) == 4) {
                    const float* px = (const float*)X + (size_t)grow * K + kb * 32 + sc * 8;
                    float4 v0 = *reinterpret_cast<const float4*>(px);
                    float4 v1 = *reinterpret_cast<const float4*>(px + 4);
                    av[0] = f2bf(v0.x); av[1] = f2bf(v0.y); av[2] = f2bf(v0.z); av[3] = f2bf(v0.w);
                    av[4] = f2bf(v1.x); av[5] = f2bf(v1.y); av[6] = f2bf(v1.z); av[7] = f2bf(v1.w);
                } else {
                    const ushort* px = (const ushort*)X + (size_t)grow * K + kb * 32 + sc * 8;
                    *reinterpret_cast<float4*>(av) = *reinterpret_cast<const float4*>(px);
                }
            } else {
#pragma unroll
                for (int j = 0; j < 8; ++j) av[j] = 0;
            }
            *reinterpret_cast<float4*>(&As[sr * 40 + sc * 8]) = *reinterpret_cast<float4*>(av);
        }
        {
            const float4* src = Wp + (size_t)kb * 512;
            reinterpret_cast<float4*>(Bs)[t]       = src[t];
            reinterpret_cast<float4*>(Bs)[t + 256] = src[t + 256];
        }
        __syncthreads();

        bf16x8 a = *reinterpret_cast<const bf16x8*>(
            &As[(w * 16 + (lane & 15)) * 40 + (lane >> 4) * 8]);
#pragma unroll
        for (int nf = 0; nf < 8; ++nf) {
            bf16x8 b = *reinterpret_cast<const bf16x8*>(&Bs[(nf * 64 + lane) * 8]);
            acc[nf] = __builtin_amdgcn_mfma_f32_16x16x32_bf16(a, b, acc[nf], 0, 0, 0);
        }
    }

    const int crow0 = row0 + w * 16 + ((lane >> 4) << 2);
    const int col   = lane & 15;
#pragma unroll
    for (int i = 0; i < 4; ++i) {
        int row = crow0 + i;
        if (row < N) {
#pragma unroll
            for (int nf = 0; nf < 8; ++nf) {
                float v = acc[nf][i];
                if constexpr (sizeof(TOut) == 2)
                    C[(size_t)row * 128 + nf * 16 + col] = (TOut)f2bf(v);
                else
                    C[(size_t)row * 128 + nf * 16 + col] = (TOut)v;
            }
        }
    }
}

// ---------------- aggregation: one wave per node, shfl-broadcast indices ----------------
// All 64 lanes cooperatively load up to 64 (csr index, dinv) pairs, broadcast via
// __shfl; gather loop 4x unrolled for >=4 outstanding 256B row gathers per wave.

template <typename TOut>
__global__ __launch_bounds__(256) void agg_k(const ushort* __restrict__ Hin,
                                             TOut* __restrict__ Hout,
                                             const int* __restrict__ csr,
                                             const int* __restrict__ start,
                                             const int* __restrict__ degc,
                                             const float* __restrict__ dinv,
                                             const float* __restrict__ bias,
                                             int N, int relu) {
    int wid  = threadIdx.x >> 6;
    int lane = threadIdx.x & 63;
    int v = blockIdx.x * 4 + wid;
    if (v >= N) return;

    float dv = dinv[v];
    int s   = start[v];
    int end = s + degc[v];

    const uint* base = reinterpret_cast<const uint*>(Hin);
    uint hp = base[(size_t)v * 64 + lane];
    float ax = dv * bf_lo(hp);
    float ay = dv * bf_hi(hp);

    for (int be = s; be < end; be += 64) {
        int m = end - be;
        if (m > 64) m = 64;
        // cooperative prefetch of indices + weights (one coalesced load each)
        int   u_l = 0;
        float w_l = 0.f;
        if (lane < m) {
            u_l = csr[be + lane];
            w_l = dinv[u_l];
        }
        int e = 0;
        for (; e + 4 <= m; e += 4) {
            int   u0 = __shfl(u_l, e),     u1 = __shfl(u_l, e + 1);
            int   u2 = __shfl(u_l, e + 2), u3 = __shfl(u_l, e + 3);
            float w0 = __shfl(w_l, e),     w1 = __shfl(w_l, e + 1);
            float w2 = __shfl(w_l, e + 2), w3 = __shfl(w_l, e + 3);
            uint p0 = base[(size_t)u0 * 64 + lane];
            uint p1 = base[(size_t)u1 * 64 + lane];
            uint p2 = base[(size_t)u2 * 64 + lane];
            uint p3 = base[(size_t)u3 * 64 + lane];
            ax = fmaf(w0, bf_lo(p0), ax); ay = fmaf(w0, bf_hi(p0), ay);
            ax = fmaf(w1, bf_lo(p1), ax); ay = fmaf(w1, bf_hi(p1), ay);
            ax = fmaf(w2, bf_lo(p2), ax); ay = fmaf(w2, bf_hi(p2), ay);
            ax = fmaf(w3, bf_lo(p3), ax); ay = fmaf(w3, bf_hi(p3), ay);
        }
        for (; e < m; ++e) {
            int   u = __shfl(u_l, e);
            float wt = __shfl(w_l, e);
            uint p = base[(size_t)u * 64 + lane];
            ax = fmaf(wt, bf_lo(p), ax);
            ay = fmaf(wt, bf_hi(p), ay);
        }
    }

    float2 b = reinterpret_cast<const float2*>(bias)[lane];
    float ox = fmaf(dv, ax, b.x);
    float oy = fmaf(dv, ay, b.y);
    if (relu) {
        ox = fmaxf(ox, 0.f);
        oy = fmaxf(oy, 0.f);
    }
    if constexpr (sizeof(TOut) == 2) {
        uint packed = (uint)f2bf(ox) | ((uint)f2bf(oy) << 16);
        reinterpret_cast<uint*>(Hout)[(size_t)v * 64 + lane] = packed;
    } else {
        reinterpret_cast<float2*>(Hout)[(size_t)v * 64 + lane] = make_float2(ox, oy);
    }
}

// ---------------- column stats + normalize ----------------

__global__ __launch_bounds__(128) void colstats_k(const float* __restrict__ H,
                                                  float* __restrict__ stats, int N) {
    int col = threadIdx.x;
    int r0 = blockIdx.x * 128;
    int r1 = r0 + 128 < N ? r0 + 128 : N;
    float s = 0.f, q = 0.f;
    for (int r = r0; r < r1; ++r) {
        float v = H[(size_t)r * 128 + col];
        s += v;
        q = fmaf(v, v, q);
    }
    atomicAdd(&stats[col], s);
    atomicAdd(&stats[128 + col], q);
}

__global__ __launch_bounds__(256) void colnorm_k(float* __restrict__ H,
                                                 const float* __restrict__ stats, int N) {
    size_t total = (size_t)N * 32;
    float invN = 1.f / (float)N;
    float invNm1 = 1.f / (float)(N - 1);
    size_t stride = (size_t)gridDim.x * blockDim.x;
    for (size_t i = (size_t)blockIdx.x * blockDim.x + threadIdx.x; i < total; i += stride) {
        int cv = (int)(i & 31);
        float4 s = reinterpret_cast<const float4*>(stats)[cv];
        float4 q = reinterpret_cast<const float4*>(stats + 128)[cv];
        float4 v = reinterpret_cast<float4*>(H)[i];
        float mu, rstd;
        mu = s.x * invN; rstd = rsqrtf((q.x - s.x * mu) * invNm1); v.x = (v.x - mu) * rstd;
        mu = s.y * invN; rstd = rsqrtf((q.y - s.y * mu) * invNm1); v.y = (v.y - mu) * rstd;
        mu = s.z * invN; rstd = rsqrtf((q.z - s.z * mu) * invNm1); v.z = (v.z - mu) * rstd;
        mu = s.w * invN; rstd = rsqrtf((q.w - s.w * mu) * invNm1); v.w = (v.w - mu) * rstd;
        reinterpret_cast<float4*>(H)[i] = v;
    }
}

// ---------------- driver ----------------

extern "C" void kernel_launch(void* const* d_in, const int* in_sizes, int n_in,
                              void* d_out, int out_size, void* d_ws, size_t ws_size,
                              hipStream_t stream) {
    const float* x1  = (const float*)d_in[0];
    const int*   ei1 = (const int*)d_in[1];
    const float* x2  = (const float*)d_in[2];
    const int*   ei2 = (const int*)d_in[3];
    const float* W0  = (const float*)d_in[4];
    const float* b0  = (const float*)d_in[5];
    const float* W1  = (const float*)d_in[6];
    const float* b1  = (const float*)d_in[7];

    const int N  = in_sizes[0] / 256;
    const int E1 = in_sizes[1] / 2;
    const int E2 = in_sizes[3] / 2;
    const int Emax = E1 > E2 ? E1 : E2;

    char* base = (char*)d_ws;
    size_t off = 0;
    auto carve = [&](size_t bytes) -> char* {
        char* p = base + off;
        off = (off + bytes + 255) & ~(size_t)255;
        return p;
    };
    ushort* hA    = (ushort*)carve((size_t)N * 128 * 2);
    ushort* hB    = (ushort*)carve((size_t)N * 128 * 2);
    float*  dinv  = (float*)carve((size_t)N * 4);
    int*    degc  = (int*)carve((size_t)N * 4);
    int*    startA= (int*)carve((size_t)N * 4);
    int*    cursor= (int*)carve((size_t)N * 4);
    int*    csr   = (int*)carve((size_t)Emax * 4);
    ushort* Wp0   = (ushort*)carve((256 / 32) * 8 * 64 * 8 * 2);
    ushort* Wp1   = (ushort*)carve((128 / 32) * 8 * 64 * 8 * 2);
    float*  stats = (float*)carve(256 * 4);
    int*    total = (int*)carve(256);

    pack_w_k<<<CDIV((256 / 32) * 8 * 64, 256), 256, 0, stream>>>(W0, Wp0, 256);
    pack_w_k<<<CDIV((128 / 32) * 8 * 64, 256), 256, 0, stream>>>(W1, Wp1, 128);

    for (int g = 0; g < 2; ++g) {
        const float* x  = g ? x2 : x1;
        const int*   ei = g ? ei2 : ei1;
        const int    E  = g ? E2 : E1;
        float* outg = (float*)d_out + (size_t)g * N * 128;

        hipMemsetAsync(degc, 0, (size_t)N * 4, stream);
        hipMemsetAsync(total, 0, 4, stream);
        hipMemsetAsync(stats, 0, 256 * 4, stream);

        int eb = CDIV(E, 256) < 4096 ? CDIV(E, 256) : 4096;
        count_deg_k<<<eb, 256, 0, stream>>>(ei + E, E, degc);
        alloc_k<<<CDIV(N, 256), 256, 0, stream>>>(degc, dinv, startA, cursor, total, N);
        fill_k<<<eb, 256, 0, stream>>>(ei, ei + E, E, cursor, csr);

        gemm_mfma<256, float, ushort><<<CDIV(N, 64), 256, 0, stream>>>(
            x, (const float4*)Wp0, hA, N);
        agg_k<ushort><<<CDIV(N, 4), 256, 0, stream>>>(hA, hB, csr, startA, degc, dinv, b0, N, 1);

        gemm_mfma<128, ushort, ushort><<<CDIV(N, 64), 256, 0, stream>>>(
            hB, (const float4*)Wp1, hA, N);
        agg_k<float><<<CDIV(N, 4), 256, 0, stream>>>(hA, outg, csr, startA, degc, dinv, b1, N, 0);

        colstats_k<<<CDIV(N, 128), 128, 0, stream>>>(outg, stats, N);
        colnorm_k<<<2048, 256, 0, stream>>>(outg, stats, N);
    }
}

// Round 4
// 529.425 us; speedup vs baseline: 2.2291x; 1.3387x over previous
//
#include <hip/hip_runtime.h>

#define CDIV(a,b) (((a)+(b)-1)/(b))

typedef __bf16 bf16x8 __attribute__((ext_vector_type(8)));
typedef float  f32x4  __attribute__((ext_vector_type(4)));

__device__ __forceinline__ ushort f2bf(float f) {
    uint u = __float_as_uint(f);
    uint r = u + 0x7fffu + ((u >> 16) & 1u);   // RNE
    return (ushort)(r >> 16);
}
__device__ __forceinline__ float bf_lo(uint p) { return __uint_as_float(p << 16); }
__device__ __forceinline__ float bf_hi(uint p) { return __uint_as_float(p & 0xffff0000u); }

// ================= CSR build via 256-node buckets =================
// bucket b = dst >> 8 covers nodes [b*256, b*256+256). Packed edge = (src<<8)|local.

// Phase A: bin edges into bucket segments (capacity CAP each).
__global__ __launch_bounds__(256) void binA_k(const int* __restrict__ src,
                                              const int* __restrict__ dst, int E,
                                              int NB, int CAP,
                                              int* __restrict__ bcur,
                                              uint* __restrict__ binned) {
    __shared__ uint hist[512];
    __shared__ uint cur[512];
    const int t = threadIdx.x;
    for (int i = t; i < NB; i += 256) hist[i] = 0;
    __syncthreads();

    const int e0 = blockIdx.x * 4096;
    const int e1 = min(e0 + 4096, E);
    for (int e = e0 + t; e < e1; e += 256)
        atomicAdd(&hist[dst[e] >> 8], 1u);
    __syncthreads();

    for (int i = t; i < NB; i += 256) {
        uint c = hist[i];
        cur[i] = c ? (uint)atomicAdd(&bcur[i], (int)c) : 0u;
    }
    __syncthreads();

    for (int e = e0 + t; e < e1; e += 256) {
        int d = dst[e];
        int b = d >> 8;
        uint p = atomicAdd(&cur[b], 1u);
        if (p < (uint)CAP)
            binned[(size_t)b * CAP + p] = ((uint)src[e] << 8) | (uint)(d & 255);
    }
}

// Phase B: one block per bucket -> csr + start/degc/dinv.
__global__ __launch_bounds__(256) void binB_k(const uint* __restrict__ binned,
                                              const int* __restrict__ bcur,
                                              int N, int CAP,
                                              int* __restrict__ csr,
                                              int* __restrict__ start,
                                              int* __restrict__ degc,
                                              float* __restrict__ dinv) {
    __shared__ uint hist[256];
    __shared__ uint cur[256];
    __shared__ uint wsum[4];
    const int b = blockIdx.x;
    const int t = threadIdx.x;
    int cnt = bcur[b];
    if (cnt > CAP) cnt = CAP;
    const uint* be = binned + (size_t)b * CAP;

    hist[t] = 0;
    __syncthreads();
    for (int e = t; e < cnt; e += 256) atomicAdd(&hist[be[e] & 255u], 1u);
    __syncthreads();

    // exclusive scan of 256 counts
    uint v = hist[t];
    uint inc = v;
#pragma unroll
    for (int off = 1; off < 64; off <<= 1) {
        uint n = __shfl_up(inc, off);
        if ((t & 63) >= off) inc += n;
    }
    if ((t & 63) == 63) wsum[t >> 6] = inc;
    __syncthreads();
    uint wo = 0;
    if ((t >> 6) >= 1) wo += wsum[0];
    if ((t >> 6) >= 2) wo += wsum[1];
    if ((t >> 6) >= 3) wo += wsum[2];
    uint excl = wo + inc - v;
    cur[t] = excl;
    __syncthreads();

    const int base = b * CAP;
    for (int e = t; e < cnt; e += 256) {
        uint w = be[e];
        uint p = atomicAdd(&cur[w & 255u], 1u);
        csr[base + (int)p] = (int)(w >> 8);
    }

    int node = b * 256 + t;
    if (node < N) {
        start[node] = base + (int)excl;
        degc[node]  = (int)v;
        dinv[node]  = rsqrtf((float)(v + 1));
    }
}

// ================= W pre-pack: fragment-major bf16 =================

__global__ __launch_bounds__(256) void pack_w_k(const float* __restrict__ W,
                                                ushort* __restrict__ Wp, int K) {
    int idx = blockIdx.x * 256 + threadIdx.x;
    int total = (K / 32) * 8 * 64;
    if (idx >= total) return;
    int l  = idx & 63;
    int nf = (idx >> 6) & 7;
    int kb = idx >> 9;
    int col = nf * 16 + (l & 15);
    int k0  = kb * 32 + (l >> 4) * 8;
    ushort o[8];
#pragma unroll
    for (int j = 0; j < 8; ++j) o[j] = f2bf(W[(size_t)(k0 + j) * 128 + col]);
    *reinterpret_cast<float4*>(Wp + (size_t)idx * 8) = *reinterpret_cast<float4*>(o);
}

// ===== MFMA GEMM with row-scale epilogue: C[r] = dinv[r] * (X[r] @ W) =====

template <int K, typename TIn>
__global__ __launch_bounds__(256) void gemm_mfma(const TIn* __restrict__ X,
                                                 const float4* __restrict__ Wp,
                                                 const float* __restrict__ dinv,
                                                 ushort* __restrict__ C, int N) {
    constexpr int KB = K / 32;
    __shared__ ushort As[64 * 40];
    __shared__ ushort Bs[8 * 64 * 8];

    const int t    = threadIdx.x;
    const int lane = t & 63;
    const int w    = t >> 6;
    const int row0 = blockIdx.x * 64;

    f32x4 acc[8] = {};

    const int sr = t >> 2;
    const int sc = t & 3;

    for (int kb = 0; kb < KB; ++kb) {
        __syncthreads();
        {
            int grow = row0 + sr;
            ushort av[8];
            if (grow < N) {
                if constexpr (sizeof(TIn) == 4) {
                    const float* px = (const float*)X + (size_t)grow * K + kb * 32 + sc * 8;
                    float4 v0 = *reinterpret_cast<const float4*>(px);
                    float4 v1 = *reinterpret_cast<const float4*>(px + 4);
                    av[0] = f2bf(v0.x); av[1] = f2bf(v0.y); av[2] = f2bf(v0.z); av[3] = f2bf(v0.w);
                    av[4] = f2bf(v1.x); av[5] = f2bf(v1.y); av[6] = f2bf(v1.z); av[7] = f2bf(v1.w);
                } else {
                    const ushort* px = (const ushort*)X + (size_t)grow * K + kb * 32 + sc * 8;
                    *reinterpret_cast<float4*>(av) = *reinterpret_cast<const float4*>(px);
                }
            } else {
#pragma unroll
                for (int j = 0; j < 8; ++j) av[j] = 0;
            }
            *reinterpret_cast<float4*>(&As[sr * 40 + sc * 8]) = *reinterpret_cast<float4*>(av);
        }
        {
            const float4* srcp = Wp + (size_t)kb * 512;
            reinterpret_cast<float4*>(Bs)[t]       = srcp[t];
            reinterpret_cast<float4*>(Bs)[t + 256] = srcp[t + 256];
        }
        __syncthreads();

        bf16x8 a = *reinterpret_cast<const bf16x8*>(
            &As[(w * 16 + (lane & 15)) * 40 + (lane >> 4) * 8]);
#pragma unroll
        for (int nf = 0; nf < 8; ++nf) {
            bf16x8 bfr = *reinterpret_cast<const bf16x8*>(&Bs[(nf * 64 + lane) * 8]);
            acc[nf] = __builtin_amdgcn_mfma_f32_16x16x32_bf16(a, bfr, acc[nf], 0, 0, 0);
        }
    }

    const int crow0 = row0 + w * 16 + ((lane >> 4) << 2);
    const int col   = lane & 15;
#pragma unroll
    for (int i = 0; i < 4; ++i) {
        int row = crow0 + i;
        if (row < N) {
            float dr = dinv[row];
#pragma unroll
            for (int nf = 0; nf < 8; ++nf)
                C[(size_t)row * 128 + nf * 16 + col] = f2bf(acc[nf][i] * dr);
        }
    }
}

// ===== aggregation: unweighted sum of pre-scaled rows, 8x unrolled gathers =====
// Hin rows are h'[u] = dinv[u] * h[u] (bf16). out[v] = dinv[v]*(h'[v] + sum h'[u]) + b.

template <typename TOut>
__global__ __launch_bounds__(256) void agg_k(const ushort* __restrict__ Hin,
                                             TOut* __restrict__ Hout,
                                             const int* __restrict__ csr,
                                             const int* __restrict__ start,
                                             const int* __restrict__ degc,
                                             const float* __restrict__ dinv,
                                             const float* __restrict__ bias,
                                             int N, int relu) {
    int wid  = threadIdx.x >> 6;
    int lane = threadIdx.x & 63;
    int v = blockIdx.x * 4 + wid;
    if (v >= N) return;

    float dv = dinv[v];
    int s   = start[v];
    int end = s + degc[v];

    const uint* base = reinterpret_cast<const uint*>(Hin);
    uint hp = base[(size_t)v * 64 + lane];
    float ax = bf_lo(hp);   // self term, already pre-scaled
    float ay = bf_hi(hp);

    for (int bs = s; bs < end; bs += 64) {
        int m = end - bs;
        if (m > 64) m = 64;
        int u_l = 0;
        if (lane < m) u_l = csr[bs + lane];
        int e = 0;
        for (; e + 8 <= m; e += 8) {
            uint p[8];
#pragma unroll
            for (int j = 0; j < 8; ++j) {
                int u = __shfl(u_l, e + j);
                p[j] = base[(size_t)u * 64 + lane];
            }
#pragma unroll
            for (int j = 0; j < 8; ++j) { ax += bf_lo(p[j]); ay += bf_hi(p[j]); }
        }
        if (e + 4 <= m) {
            uint p[4];
#pragma unroll
            for (int j = 0; j < 4; ++j) {
                int u = __shfl(u_l, e + j);
                p[j] = base[(size_t)u * 64 + lane];
            }
#pragma unroll
            for (int j = 0; j < 4; ++j) { ax += bf_lo(p[j]); ay += bf_hi(p[j]); }
            e += 4;
        }
        for (; e < m; ++e) {
            int u = __shfl(u_l, e);
            uint p = base[(size_t)u * 64 + lane];
            ax += bf_lo(p);
            ay += bf_hi(p);
        }
    }

    float2 b = reinterpret_cast<const float2*>(bias)[lane];
    float ox = fmaf(dv, ax, b.x);
    float oy = fmaf(dv, ay, b.y);
    if (relu) {
        ox = fmaxf(ox, 0.f);
        oy = fmaxf(oy, 0.f);
    }
    if constexpr (sizeof(TOut) == 2) {
        uint packed = (uint)f2bf(ox) | ((uint)f2bf(oy) << 16);
        reinterpret_cast<uint*>(Hout)[(size_t)v * 64 + lane] = packed;
    } else {
        reinterpret_cast<float2*>(Hout)[(size_t)v * 64 + lane] = make_float2(ox, oy);
    }
}

// ================= column stats + normalize =================

__global__ __launch_bounds__(128) void colstats_k(const float* __restrict__ H,
                                                  float* __restrict__ stats, int N) {
    int col = threadIdx.x;
    int r0 = blockIdx.x * 128;
    int r1 = r0 + 128 < N ? r0 + 128 : N;
    float s = 0.f, q = 0.f;
    for (int r = r0; r < r1; ++r) {
        float v = H[(size_t)r * 128 + col];
        s += v;
        q = fmaf(v, v, q);
    }
    atomicAdd(&stats[col], s);
    atomicAdd(&stats[128 + col], q);
}

__global__ __launch_bounds__(256) void colnorm_k(float* __restrict__ H,
                                                 const float* __restrict__ stats, int N) {
    size_t total = (size_t)N * 32;
    float invN = 1.f / (float)N;
    float invNm1 = 1.f / (float)(N - 1);
    size_t stride = (size_t)gridDim.x * blockDim.x;
    for (size_t i = (size_t)blockIdx.x * blockDim.x + threadIdx.x; i < total; i += stride) {
        int cv = (int)(i & 31);
        float4 s = reinterpret_cast<const float4*>(stats)[cv];
        float4 q = reinterpret_cast<const float4*>(stats + 128)[cv];
        float4 v = reinterpret_cast<float4*>(H)[i];
        float mu, rstd;
        mu = s.x * invN; rstd = rsqrtf((q.x - s.x * mu) * invNm1); v.x = (v.x - mu) * rstd;
        mu = s.y * invN; rstd = rsqrtf((q.y - s.y * mu) * invNm1); v.y = (v.y - mu) * rstd;
        mu = s.z * invN; rstd = rsqrtf((q.z - s.z * mu) * invNm1); v.z = (v.z - mu) * rstd;
        mu = s.w * invN; rstd = rsqrtf((q.w - s.w * mu) * invNm1); v.w = (v.w - mu) * rstd;
        reinterpret_cast<float4*>(H)[i] = v;
    }
}

// ================= driver =================

extern "C" void kernel_launch(void* const* d_in, const int* in_sizes, int n_in,
                              void* d_out, int out_size, void* d_ws, size_t ws_size,
                              hipStream_t stream) {
    const float* x1  = (const float*)d_in[0];
    const int*   ei1 = (const int*)d_in[1];
    const float* x2  = (const float*)d_in[2];
    const int*   ei2 = (const int*)d_in[3];
    const float* W0  = (const float*)d_in[4];
    const float* b0  = (const float*)d_in[5];
    const float* W1  = (const float*)d_in[6];
    const float* b1  = (const float*)d_in[7];

    const int N  = in_sizes[0] / 256;
    const int E1 = in_sizes[1] / 2;
    const int E2 = in_sizes[3] / 2;
    const int Emax = E1 > E2 ? E1 : E2;

    const int NB  = CDIV(N, 256);                 // buckets of 256 dst nodes
    int cap = (Emax / NB) * 8 / 5 + 1024;         // ~1.6x expected + slack
    const int CAP = (cap + 1023) & ~1023;

    char* base = (char*)d_ws;
    size_t off = 0;
    auto carve = [&](size_t bytes) -> char* {
        char* p = base + off;
        off = (off + bytes + 255) & ~(size_t)255;
        return p;
    };
    ushort* hA    = (ushort*)carve((size_t)N * 128 * 2);   // also aliases `binned`
    ushort* hB    = (ushort*)carve((size_t)N * 128 * 2);
    float*  dinv  = (float*)carve((size_t)N * 4);
    int*    degc  = (int*)carve((size_t)N * 4);
    int*    startA= (int*)carve((size_t)N * 4);
    int*    csr   = (int*)carve((size_t)NB * CAP * 4);
    ushort* Wp0   = (ushort*)carve((256 / 32) * 8 * 64 * 8 * 2);
    ushort* Wp1   = (ushort*)carve((128 / 32) * 8 * 64 * 8 * 2);
    float*  stats = (float*)carve(256 * 4);
    int*    bcur  = (int*)carve((size_t)NB * 4);
    uint*   binned = (uint*)hA;  // alias: consumed by binB before gemm1 writes hA

    pack_w_k<<<CDIV((256 / 32) * 8 * 64, 256), 256, 0, stream>>>(W0, Wp0, 256);
    pack_w_k<<<CDIV((128 / 32) * 8 * 64, 256), 256, 0, stream>>>(W1, Wp1, 128);

    for (int g = 0; g < 2; ++g) {
        const float* x  = g ? x2 : x1;
        const int*   ei = g ? ei2 : ei1;
        const int    E  = g ? E2 : E1;
        float* outg = (float*)d_out + (size_t)g * N * 128;

        hipMemsetAsync(bcur, 0, (size_t)NB * 4, stream);
        hipMemsetAsync(stats, 0, 256 * 4, stream);

        // CSR build (bucketed)
        binA_k<<<CDIV(E, 4096), 256, 0, stream>>>(ei, ei + E, E, NB, CAP, bcur, binned);
        binB_k<<<NB, 256, 0, stream>>>(binned, bcur, N, CAP, csr, startA, degc, dinv);

        // conv1: hA = dinv .* (x @ W0) ; hB = relu(dinv.*sum + b0)
        gemm_mfma<256, float><<<CDIV(N, 64), 256, 0, stream>>>(
            x, (const float4*)Wp0, dinv, hA, N);
        agg_k<ushort><<<CDIV(N, 4), 256, 0, stream>>>(hA, hB, csr, startA, degc, dinv, b0, N, 1);

        // conv2: hA = dinv .* (hB @ W1) ; out = dinv.*sum + b1 (f32)
        gemm_mfma<128, ushort><<<CDIV(N, 64), 256, 0, stream>>>(
            hB, (const float4*)Wp1, dinv, hA, N);
        agg_k<float><<<CDIV(N, 4), 256, 0, stream>>>(hA, outg, csr, startA, degc, dinv, b1, N, 0);

        colstats_k<<<CDIV(N, 128), 128, 0, stream>>>(outg, stats, N);
        colnorm_k<<<2048, 256, 0, stream>>>(outg, stats, N);
    }
}